// Round 6
// baseline (234.611 us; speedup 1.0000x reference)
//
#include <hip/hip_runtime.h>
#include <math.h>

#define BSZ 32
#define CCH 192
#define NPIX 784
#define NP 896          // padded N (56 groups of 16)
#define NGRP 56
#define OUTC 384
#define KNN 9
#define CING 96
#define COUTG 96

typedef short s8v __attribute__((ext_vector_type(8)));
typedef float f4v __attribute__((ext_vector_type(4)));

// ---------------- ws layout ----------------
// xf*: [b][g(56)][kc(6)][lane(64)][8] bf16 RAW x fragments -> per batch 344 KB
#define XFH_BYTES ((size_t)BSZ * NGRP * 6 * 64 * 8 * 2)   // 11,010,048
#define XFL_BYTES XFH_BYTES
#define PAIR_BYTES ((size_t)BSZ * NP * 8)                 //    229,376  {sq, inv} per node
#define IDX_BYTES ((size_t)BSZ * NPIX * KNN * 4)          //    903,168
// tbuf: BSZ*192*NPIX*4 = 19,267,584   total 42,420,224

__device__ __forceinline__ float gelu_exact(float u) {
    return 0.5f * u * (1.0f + erff(u * 0.70710678118654752440f));
}
__device__ __forceinline__ ushort bf16_rne(float f) {
    uint u = __float_as_uint(f);
    uint r = (u + 0x7fffu + ((u >> 16) & 1u)) >> 16;
    return (ushort)r;
}
__device__ __forceinline__ float bf16f(ushort h) { return __uint_as_float(((uint)h) << 16); }

// ---------------- K1: coalesced load -> RAW bf16 hi/lo fragments + {sq,inv} ----------------
__global__ __launch_bounds__(256) void k1_normalize(const float* __restrict__ x,
                                                    ushort* __restrict__ xfh,
                                                    ushort* __restrict__ xfl,
                                                    float2* __restrict__ pair) {
    __shared__ float xs[CCH][65];
    int b = blockIdx.y;
    int n0 = blockIdx.x * 64;
    int t = threadIdx.x;
    const float* xb = x + (size_t)b * CCH * NPIX;

    for (int i = t; i < CCH * 64; i += 256) {
        int c = i >> 6, j = i & 63, n = n0 + j;
        xs[c][j] = (n < NPIX) ? xb[c * NPIX + n] : 0.f;
    }
    __syncthreads();

    {
        int j = t >> 2, part = t & 3;
        float ss = 0.f;
        for (int k = 0; k < 48; ++k) { float v = xs[part * 48 + k][j]; ss = fmaf(v, v, ss); }
        ss += __shfl_xor(ss, 1);
        ss += __shfl_xor(ss, 2);
        float inv = 1.0f / fmaxf(sqrtf(ss), 1e-12f);
        // ref-matching sq: sum of squares of fp32-normalized values
        float s2 = 0.f;
        for (int k = 0; k < 48; ++k) {
            float v = xs[part * 48 + k][j] * inv;
            s2 = fmaf(v, v, s2);
        }
        s2 += __shfl_xor(s2, 1);
        s2 += __shfl_xor(s2, 2);
        if (part == 0) {
            int n = n0 + j;
            pair[b * NP + n] = (n < NPIX) ? make_float2(s2, inv) : make_float2(1e30f, 0.f);
        }
    }

    // fragment emission: 4 groups x 6 kc x 64 lanes = 1536 chunks of 8
#pragma unroll
    for (int i = 0; i < 6; ++i) {
        int ch = t + i * 256;
        int g = ch / 384, rem = ch - g * 384;
        int kc = rem >> 6, l = rem & 63;
        int nl = g * 16 + (l & 15);
        int c0 = kc * 32 + (l >> 4) * 8;
        s8v hv, lv;
#pragma unroll
        for (int k = 0; k < 8; ++k) {
            float v = xs[c0 + k][nl];
            ushort h = bf16_rne(v);
            hv[k] = (short)h;
            lv[k] = (short)bf16_rne(v - bf16f(h));
        }
        size_t doff = (((size_t)(b * NGRP + (n0 >> 4) + g)) * 6 + kc) * 512 + (size_t)l * 8;
        *(s8v*)(xfh + doff) = hv;
        *(s8v*)(xfl + doff) = lv;
    }
}

// ---------------- K2: MFMA knn, exact key, branchless med3 top-9 + index recovery ----------------
__device__ __forceinline__ bool lt_pair(float v, int id, float dv, int di) {
    return (v < dv) || (v == dv && id < di);
}
__device__ __forceinline__ void ins9p(float (&d)[KNN], int (&ii)[KNN], float v, int id) {
    if (!lt_pair(v, id, d[KNN - 1], ii[KNN - 1])) return;
    bool cprev = true;
#pragma unroll
    for (int p = KNN - 1; p >= 0; --p) {
        bool cp = (p == 0) ? false : lt_pair(v, id, d[p - 1], ii[p - 1]);
        float nd = cp ? d[p - 1] : (cprev ? v : d[p]);
        int nid = cp ? ii[p - 1] : (cprev ? id : ii[p]);
        d[p] = nd; ii[p] = nid; cprev = cp;
    }
}

__global__ __launch_bounds__(128, 2) void k2_knn(const ushort* __restrict__ xfh,
                                                 const ushort* __restrict__ xfl,
                                                 const float* __restrict__ pair,
                                                 int* __restrict__ nnidx) {
    __shared__ float dls[2][64][KNN];
    __shared__ int   ils[2][64][KNN];
    __shared__ unsigned long long sk[16][128];
    int wg = blockIdx.x;                       // 1568 = 8 xcd * (4 b * 49 qt)
    int b  = (wg & 7) * 4 + (wg >> 3) / 49;
    int qt = (wg >> 3) % 49;
    int t = threadIdx.x, w = t >> 6, l = t & 63;
    int lk = l >> 4;
    const ushort* fh = xfh + (size_t)b * NGRP * 3072;
    const ushort* fl = xfl + (size_t)b * NGRP * 3072;
    const float* pb = pair + (size_t)b * NP * 2;
    int l8 = l * 8;

    // resident query fragments (16 queries of group qt)
    s8v qh[6], ql[6];
#pragma unroll
    for (int kc = 0; kc < 6; ++kc) {
        qh[kc] = *(const s8v*)(fh + (size_t)qt * 3072 + kc * 512 + l8);
        ql[kc] = *(const s8v*)(fl + (size_t)qt * 3072 + kc * 512 + l8);
    }
    float c2q = -2.f * pb[(qt * 16 + (l & 15)) * 2 + 1];   // -2 * inv_q for this lane's query

    // pass 1: values-only top-9 via branchless med3 chain; stash all keys in regs
    float d0 = 3.4e38f, d1 = 3.4e38f, d2 = 3.4e38f, d3 = 3.4e38f, d4 = 3.4e38f,
          d5 = 3.4e38f, d6 = 3.4e38f, d7 = 3.4e38f, d8 = 3.4e38f;
    float da[112];
#pragma unroll
    for (int cg0 = 0; cg0 < 28; ++cg0) {
        int cg = w * 28 + cg0;
        const ushort* ch = fh + (size_t)cg * 3072 + l8;
        const ushort* cl = fl + (size_t)cg * 3072 + l8;
        f4v aH = {0.f, 0.f, 0.f, 0.f};
        f4v aX = {0.f, 0.f, 0.f, 0.f};
#pragma unroll
        for (int kc = 0; kc < 6; ++kc) {
            s8v vh = *(const s8v*)(ch + kc * 512);
            s8v vl = *(const s8v*)(cl + kc * 512);
            aH = __builtin_amdgcn_mfma_f32_16x16x32_bf16(vh, qh[kc], aH, 0, 0, 0);
            aX = __builtin_amdgcn_mfma_f32_16x16x32_bf16(vl, qh[kc], aX, 0, 0, 0);
            aX = __builtin_amdgcn_mfma_f32_16x16x32_bf16(vh, ql[kc], aX, 0, 0, 0);
            aX = __builtin_amdgcn_mfma_f32_16x16x32_bf16(vl, ql[kc], aX, 0, 0, 0);
        }
        float4 pA = *(const float4*)(pb + (size_t)(cg * 16 + lk * 4) * 2);
        float4 pB = *(const float4*)(pb + (size_t)(cg * 16 + lk * 4) * 2 + 4);
        float sqn_[4] = {pA.x, pA.z, pB.x, pB.z};
        float inv_[4] = {pA.y, pA.w, pB.y, pB.w};
#pragma unroll
        for (int r = 0; r < 4; ++r) {
            // key = sq_n - 2*inv_q*inv_n*dot_raw  (pads: inv=0,sq=1e30 -> 1e30)
            float v = fmaf(c2q * inv_[r], aH[r] + aX[r], sqn_[r]);
            da[cg0 * 4 + r] = v;
            d8 = __builtin_amdgcn_fmed3f(v, d7, d8);
            d7 = __builtin_amdgcn_fmed3f(v, d6, d7);
            d6 = __builtin_amdgcn_fmed3f(v, d5, d6);
            d5 = __builtin_amdgcn_fmed3f(v, d4, d5);
            d4 = __builtin_amdgcn_fmed3f(v, d3, d4);
            d3 = __builtin_amdgcn_fmed3f(v, d2, d3);
            d2 = __builtin_amdgcn_fmed3f(v, d1, d2);
            d1 = __builtin_amdgcn_fmed3f(v, d0, d1);
            d0 = fminf(v, d0);
        }
    }

    // pass 2: collect entries <= kth into per-lane LDS stack
    float kth = d8;
    uint cnt = 0;
#pragma unroll
    for (int i = 0; i < 112; ++i) {
        float v = da[i];
        if (v <= kth) {
            int id = (w * 28 + (i >> 2)) * 16 + lk * 4 + (i & 3);
            sk[cnt][t] = ((unsigned long long)__float_as_uint(v) << 32) | (uint)id;
            cnt = cnt < 15u ? cnt + 1u : 15u;
        }
    }

    // drain: exact (dist,idx) lex sort of ~9 entries
    float d9[KNN]; int i9[KNN];
#pragma unroll
    for (int r = 0; r < KNN; ++r) { d9[r] = 3.4e38f; i9[r] = 0x7fffffff; }
    for (int j = 0; j < 16; ++j) {
        if (!__any((int)((uint)j < cnt))) break;
        if ((uint)j < cnt) {
            unsigned long long pv = sk[j][t];
            ins9p(d9, i9, __uint_as_float((uint)(pv >> 32)), (int)(uint)(pv & 0xffffffffu));
        }
    }

#pragma unroll
    for (int r = 0; r < KNN; ++r) { dls[w][l][r] = d9[r]; ils[w][l][r] = i9[r]; }
    __syncthreads();
    if (t < 16) {
        int q = qt * 16 + t;
        int pk[8] = {0, 0, 0, 0, 0, 0, 0, 0};
        int* op = nnidx + ((size_t)b * NPIX + q) * KNN;
        for (int r = 0; r < KNN; ++r) {
            float best = 3.4e38f; int bi = 0x7fffffff; int bk = 0;
#pragma unroll
            for (int m = 0; m < 8; ++m) {
                int ww = m >> 2, kk = m & 3;
                int idx = pk[m] < KNN ? pk[m] : KNN - 1;
                float v = dls[ww][kk * 16 + t][idx];
                int ii = ils[ww][kk * 16 + t][idx];
                if (pk[m] < KNN && lt_pair(v, ii, best, bi)) { best = v; bi = ii; bk = m; }
            }
            op[r] = bi;
#pragma unroll
            for (int m = 0; m < 8; ++m) pk[m] += (m == bk) ? 1 : 0;
        }
    }
}

// ---------------- K3: MFMA projection t[og,n] = dot96(w[og], x[half,:,n]) ----------------
// A = X raw frags (n rows), B = W hi/lo built on the fly (og cols). Markidis 3x.
__global__ __launch_bounds__(256, 2) void k3_proj(const ushort* __restrict__ xfh,
                                                  const ushort* __restrict__ xfl,
                                                  const float* __restrict__ w,
                                                  const float* __restrict__ bias,
                                                  float* __restrict__ out,
                                                  float* __restrict__ tbuf) {
    int wg = blockIdx.x;                       // 1568 = 8 xcd * (4 b * 49 ng)
    int b  = (wg & 7) * 4 + (wg >> 3) / 49;
    int ng = (wg >> 3) % 49;
    int t = threadIdx.x, g = t >> 6, l = t & 63;
    int h = l >> 4, m16 = l & 15;
    int kb = (g & 1) * 3;

    const ushort* fh = xfh + (((size_t)(b * NGRP + ng)) * 6 + kb) * 512 + (size_t)l * 8;
    const ushort* fl = xfl + (((size_t)(b * NGRP + ng)) * 6 + kb) * 512 + (size_t)l * 8;
    s8v xh[3], xl[3];
#pragma unroll
    for (int kk = 0; kk < 3; ++kk) {
        xh[kk] = *(const s8v*)(fh + kk * 512);
        xl[kk] = *(const s8v*)(fl + kk * 512);
    }

    for (int ogg = 0; ogg < 6; ++ogg) {
        int row = g * 96 + ogg * 16 + m16;     // global out-channel
        const float* wr = w + row * 96 + h * 8;
        s8v wh[3], wl[3];
#pragma unroll
        for (int kk = 0; kk < 3; ++kk) {
            float4 wa = *(const float4*)(wr + kk * 32);
            float4 wb = *(const float4*)(wr + kk * 32 + 4);
            float vv[8] = {wa.x, wa.y, wa.z, wa.w, wb.x, wb.y, wb.z, wb.w};
#pragma unroll
            for (int k = 0; k < 8; ++k) {
                ushort hh = bf16_rne(vv[k]);
                wh[kk][k] = (short)hh;
                wl[kk][k] = (short)bf16_rne(vv[k] - bf16f(hh));
            }
        }
        f4v acc = {0.f, 0.f, 0.f, 0.f};
#pragma unroll
        for (int kk = 0; kk < 3; ++kk) {
            acc = __builtin_amdgcn_mfma_f32_16x16x32_bf16(xh[kk], wh[kk], acc, 0, 0, 0);
            acc = __builtin_amdgcn_mfma_f32_16x16x32_bf16(xh[kk], wl[kk], acc, 0, 0, 0);
            acc = __builtin_amdgcn_mfma_f32_16x16x32_bf16(xl[kk], wh[kk], acc, 0, 0, 0);
        }
        // D: n = ng*16 + h*4 + r, og-col = m16
        if (g < 2) {
            float bv = bias[row];
#pragma unroll
            for (int r = 0; r < 4; ++r) {
                int n = ng * 16 + h * 4 + r;
                out[((size_t)b * OUTC + row) * NPIX + n] = gelu_exact(acc[r] + bv);
            }
        } else {
            int r2 = (g - 2) * 96 + ogg * 16 + m16;
#pragma unroll
            for (int r = 0; r < 4; ++r) {
                int n = ng * 16 + h * 4 + r;
                tbuf[((size_t)b * 192 + r2) * NPIX + n] = acc[r];
            }
        }
    }
}

// ---------------- K4: groups 2/3  out = max_k gelu(t[idx_k] - t[n] + bias) ----------------
// gelu is unimodal (min at u*~-0.752): max over set = max(gelu(umin), gelu(umax))
__global__ __launch_bounds__(256) void k4_gather(const float* __restrict__ tbuf,
                                                 const int* __restrict__ nnidx,
                                                 const float* __restrict__ bias,
                                                 float* __restrict__ out) {
    __shared__ float trow[NPIX];
    int og2 = blockIdx.x;    // 0..191
    int b = blockIdx.y;
    int t = threadIdx.x;
    const float* tr = tbuf + ((size_t)b * 192 + og2) * NPIX;
    for (int i = t; i < NPIX; i += 256) trow[i] = tr[i];
    __syncthreads();
    float bv = bias[192 + og2];
    for (int n = t; n < NPIX; n += 256) {
        float ti = trow[n];
        const int* ip = nnidx + ((size_t)b * NPIX + n) * KNN;
        float umin = 3.4e38f, umax = -3.4e38f;
#pragma unroll
        for (int k = 0; k < KNN; ++k) {
            int j = ip[k];
            float u = trow[j] - ti + bv;
            umin = fminf(umin, u);
            umax = fmaxf(umax, u);
        }
        float m = fmaxf(gelu_exact(umin), gelu_exact(umax));
        out[((size_t)b * OUTC + 192 + og2) * NPIX + n] = m;
    }
}

extern "C" void kernel_launch(void* const* d_in, const int* in_sizes, int n_in,
                              void* d_out, int out_size, void* d_ws, size_t ws_size,
                              hipStream_t stream) {
    const float* x    = (const float*)d_in[0];
    const float* w    = (const float*)d_in[1];
    const float* bias = (const float*)d_in[2];
    float* out = (float*)d_out;
    char* ws = (char*)d_ws;

    ushort* xfh   = (ushort*)(ws);
    ushort* xfl   = (ushort*)(ws + XFH_BYTES);
    float2* pair  = (float2*)(ws + XFH_BYTES + XFL_BYTES);
    int*    nnidx = (int*)   (ws + XFH_BYTES + XFL_BYTES + PAIR_BYTES);
    float*  tbuf  = (float*) (ws + XFH_BYTES + XFL_BYTES + PAIR_BYTES + IDX_BYTES);

    k1_normalize<<<dim3(NP / 64, BSZ), 256, 0, stream>>>(x, xfh, xfl, pair);
    k2_knn<<<dim3(1568), 128, 0, stream>>>(xfh, xfl, (const float*)pair, nnidx);
    k3_proj<<<dim3(1568), 256, 0, stream>>>(xfh, xfl, w, bias, out, tbuf);
    k4_gather<<<dim3(192, BSZ), 256, 0, stream>>>(tbuf, nnidx, bias, out);
}

// Round 8
// 173.806 us; speedup vs baseline: 1.3498x; 1.3498x over previous
//
#include <hip/hip_runtime.h>
#include <math.h>

#define BSZ 32
#define CCH 192
#define NPIX 784
#define NP 896          // padded N (56 groups of 16)
#define NGRP 56
#define OUTC 384
#define KNN 9
#define CING 96
#define COUTG 96

typedef short s8v __attribute__((ext_vector_type(8)));
typedef float f4v __attribute__((ext_vector_type(4)));

// ---------------- ws layout ----------------
// xf*: [b][g(56)][kc(6)][lane(64)][8] bf16 RAW x fragments -> per batch 344 KB
#define XFH_BYTES ((size_t)BSZ * NGRP * 6 * 64 * 8 * 2)   // 11,010,048
#define XFL_BYTES XFH_BYTES
#define PAIR_BYTES ((size_t)BSZ * NP * 8)                 //    229,376  {sq, inv} per node
#define IDX_BYTES ((size_t)BSZ * NPIX * KNN * 4)          //    903,168
// tbuf: BSZ*192*NPIX*4 = 19,267,584   total 42,420,224

__device__ __forceinline__ float gelu_exact(float u) {
    return 0.5f * u * (1.0f + erff(u * 0.70710678118654752440f));
}
__device__ __forceinline__ ushort bf16_rne(float f) {
    uint u = __float_as_uint(f);
    uint r = (u + 0x7fffu + ((u >> 16) & 1u)) >> 16;
    return (ushort)r;
}
__device__ __forceinline__ float bf16f(ushort h) { return __uint_as_float(((uint)h) << 16); }

// ---------------- K1: coalesced load -> RAW bf16 hi/lo fragments + {sq,inv} ----------------
__global__ __launch_bounds__(256) void k1_normalize(const float* __restrict__ x,
                                                    ushort* __restrict__ xfh,
                                                    ushort* __restrict__ xfl,
                                                    float2* __restrict__ pair) {
    __shared__ float xs[CCH][65];
    int b = blockIdx.y;
    int n0 = blockIdx.x * 64;
    int t = threadIdx.x;
    const float* xb = x + (size_t)b * CCH * NPIX;

    for (int i = t; i < CCH * 64; i += 256) {
        int c = i >> 6, j = i & 63, n = n0 + j;
        xs[c][j] = (n < NPIX) ? xb[c * NPIX + n] : 0.f;
    }
    __syncthreads();

    {
        int j = t >> 2, part = t & 3;
        float ss = 0.f;
        for (int k = 0; k < 48; ++k) { float v = xs[part * 48 + k][j]; ss = fmaf(v, v, ss); }
        ss += __shfl_xor(ss, 1);
        ss += __shfl_xor(ss, 2);
        float inv = 1.0f / fmaxf(sqrtf(ss), 1e-12f);
        // ref-matching sq: sum of squares of fp32-normalized values
        float s2 = 0.f;
        for (int k = 0; k < 48; ++k) {
            float v = xs[part * 48 + k][j] * inv;
            s2 = fmaf(v, v, s2);
        }
        s2 += __shfl_xor(s2, 1);
        s2 += __shfl_xor(s2, 2);
        if (part == 0) {
            int n = n0 + j;
            pair[b * NP + n] = (n < NPIX) ? make_float2(s2, inv) : make_float2(1e30f, 0.f);
        }
    }

    // fragment emission: 4 groups x 6 kc x 64 lanes = 1536 chunks of 8
#pragma unroll
    for (int i = 0; i < 6; ++i) {
        int ch = t + i * 256;
        int g = ch / 384, rem = ch - g * 384;
        int kc = rem >> 6, l = rem & 63;
        int nl = g * 16 + (l & 15);
        int c0 = kc * 32 + (l >> 4) * 8;
        s8v hv, lv;
#pragma unroll
        for (int k = 0; k < 8; ++k) {
            float v = xs[c0 + k][nl];
            ushort h = bf16_rne(v);
            hv[k] = (short)h;
            lv[k] = (short)bf16_rne(v - bf16f(h));
        }
        size_t doff = (((size_t)(b * NGRP + (n0 >> 4) + g)) * 6 + kc) * 512 + (size_t)l * 8;
        *(s8v*)(xfh + doff) = hv;
        *(s8v*)(xfl + doff) = lv;
    }
}

// ---------------- K2: MFMA knn, med3 value chain + drain-on-full index stack ----------------
__device__ __forceinline__ bool lt_pair(float v, int id, float dv, int di) {
    return (v < dv) || (v == dv && id < di);
}
__device__ __forceinline__ void ins9p(float (&d)[KNN], int (&ii)[KNN], float v, int id) {
    if (!lt_pair(v, id, d[KNN - 1], ii[KNN - 1])) return;
    bool cprev = true;
#pragma unroll
    for (int p = KNN - 1; p >= 0; --p) {
        bool cp = (p == 0) ? false : lt_pair(v, id, d[p - 1], ii[p - 1]);
        float nd = cp ? d[p - 1] : (cprev ? v : d[p]);
        int nid = cp ? ii[p - 1] : (cprev ? id : ii[p]);
        d[p] = nd; ii[p] = nid; cprev = cp;
    }
}

__global__ __launch_bounds__(128, 3) void k2_knn(const ushort* __restrict__ xfh,
                                                 const ushort* __restrict__ xfl,
                                                 const float* __restrict__ pair,
                                                 int* __restrict__ nnidx) {
    __shared__ float dls[2][64][KNN];
    __shared__ int   ils[2][64][KNN];
    __shared__ unsigned long long sk[16][128];
    int wg = blockIdx.x;                       // 1568 = 8 xcd * (4 b * 49 qt)
    int b  = (wg & 7) * 4 + (wg >> 3) / 49;
    int qt = (wg >> 3) % 49;
    int t = threadIdx.x, w = t >> 6, l = t & 63;
    int lk = l >> 4;
    const ushort* fh = xfh + (size_t)b * NGRP * 3072;
    const ushort* fl = xfl + (size_t)b * NGRP * 3072;
    const float* pb = pair + (size_t)b * NP * 2;
    int l8 = l * 8;

    // resident query fragments (16 queries of group qt)
    s8v qh[6], ql[6];
#pragma unroll
    for (int kc = 0; kc < 6; ++kc) {
        qh[kc] = *(const s8v*)(fh + (size_t)qt * 3072 + kc * 512 + l8);
        ql[kc] = *(const s8v*)(fl + (size_t)qt * 3072 + kc * 512 + l8);
    }
    float c2q = -2.f * pb[(qt * 16 + (l & 15)) * 2 + 1];   // -2 * inv_q for this lane's query

    // running exact (v,idx) top-9 (drain target) + values-only med3 chain
    float d9[KNN]; int i9[KNN];
#pragma unroll
    for (int r = 0; r < KNN; ++r) { d9[r] = 3.4e38f; i9[r] = 0x7fffffff; }
    float d0 = 3.4e38f, d1 = 3.4e38f, d2 = 3.4e38f, d3 = 3.4e38f, d4 = 3.4e38f,
          d5 = 3.4e38f, d6 = 3.4e38f, d7 = 3.4e38f, d8 = 3.4e38f;
    uint cnt = 0;

    for (int cg0 = 0; cg0 < 28; ++cg0) {
        int cg = w * 28 + cg0;
        const ushort* ch = fh + (size_t)cg * 3072 + l8;
        const ushort* cl = fl + (size_t)cg * 3072 + l8;
        f4v aH = {0.f, 0.f, 0.f, 0.f};
        f4v aX = {0.f, 0.f, 0.f, 0.f};
#pragma unroll
        for (int kc = 0; kc < 6; ++kc) {
            s8v vh = *(const s8v*)(ch + kc * 512);
            s8v vl = *(const s8v*)(cl + kc * 512);
            aH = __builtin_amdgcn_mfma_f32_16x16x32_bf16(vh, qh[kc], aH, 0, 0, 0);
            aX = __builtin_amdgcn_mfma_f32_16x16x32_bf16(vl, qh[kc], aX, 0, 0, 0);
            aX = __builtin_amdgcn_mfma_f32_16x16x32_bf16(vh, ql[kc], aX, 0, 0, 0);
            aX = __builtin_amdgcn_mfma_f32_16x16x32_bf16(vl, ql[kc], aX, 0, 0, 0);
        }
        float4 pA = *(const float4*)(pb + (size_t)(cg * 16 + lk * 4) * 2);
        float4 pB = *(const float4*)(pb + (size_t)(cg * 16 + lk * 4) * 2 + 4);
        float sqn_[4] = {pA.x, pA.z, pB.x, pB.z};
        float inv_[4] = {pA.y, pA.w, pB.y, pB.w};
#pragma unroll
        for (int r = 0; r < 4; ++r) {
            // key = sq_n - 2*inv_q*inv_n*dot_raw  (pads: inv=0,sq=1e30 -> 1e30)
            float v = fmaf(c2q * inv_[r], aH[r] + aX[r], sqn_[r]);
            d8 = __builtin_amdgcn_fmed3f(v, d7, d8);
            d7 = __builtin_amdgcn_fmed3f(v, d6, d7);
            d6 = __builtin_amdgcn_fmed3f(v, d5, d6);
            d5 = __builtin_amdgcn_fmed3f(v, d4, d5);
            d4 = __builtin_amdgcn_fmed3f(v, d3, d4);
            d3 = __builtin_amdgcn_fmed3f(v, d2, d3);
            d2 = __builtin_amdgcn_fmed3f(v, d1, d2);
            d1 = __builtin_amdgcn_fmed3f(v, d0, d1);
            d0 = fminf(v, d0);
            if (v <= d8) {   // v is in the running top-9 -> candidate for final set
                int id = cg * 16 + lk * 4 + r;
                sk[cnt][t] = ((unsigned long long)__float_as_uint(v) << 32) | (uint)id;
                ++cnt;       // cnt <= 12 entering a tile, <= 16 after -> no overflow
            }
        }
        // wave-synchronized drain keeps per-candidate path tiny
        if (__any((int)(cnt >= 13u))) {
#pragma unroll 1
            for (int j = 0; j < 16; ++j) {
                if ((uint)j < cnt) {
                    unsigned long long pv = sk[j][t];
                    ins9p(d9, i9, __uint_as_float((uint)(pv >> 32)), (int)(uint)(pv & 0xffffffffu));
                }
            }
            cnt = 0;
        }
    }
    // final drain
#pragma unroll 1
    for (int j = 0; j < 16; ++j) {
        if ((uint)j < cnt) {
            unsigned long long pv = sk[j][t];
            ins9p(d9, i9, __uint_as_float((uint)(pv >> 32)), (int)(uint)(pv & 0xffffffffu));
        }
    }

#pragma unroll
    for (int r = 0; r < KNN; ++r) { dls[w][l][r] = d9[r]; ils[w][l][r] = i9[r]; }
    __syncthreads();
    if (t < 16) {
        int q = qt * 16 + t;
        int pk[8] = {0, 0, 0, 0, 0, 0, 0, 0};
        int* op = nnidx + ((size_t)b * NPIX + q) * KNN;
        for (int r = 0; r < KNN; ++r) {
            float best = 3.4e38f; int bi = 0x7fffffff; int bk = 0;
#pragma unroll
            for (int m = 0; m < 8; ++m) {
                int ww = m >> 2, kk = m & 3;
                int idx = pk[m] < KNN ? pk[m] : KNN - 1;
                float v = dls[ww][kk * 16 + t][idx];
                int ii = ils[ww][kk * 16 + t][idx];
                if (pk[m] < KNN && lt_pair(v, ii, best, bi)) { best = v; bi = ii; bk = m; }
            }
            op[r] = bi;
#pragma unroll
            for (int m = 0; m < 8; ++m) pk[m] += (m == bk) ? 1 : 0;
        }
    }
}

// ---------------- K3: MFMA projection t[og,n] = dot96(w[og], x[half,:,n]) ----------------
// A = X raw frags (n rows), B = W hi/lo built on the fly (og cols). Markidis 3x.
__global__ __launch_bounds__(256, 2) void k3_proj(const ushort* __restrict__ xfh,
                                                  const ushort* __restrict__ xfl,
                                                  const float* __restrict__ w,
                                                  const float* __restrict__ bias,
                                                  float* __restrict__ out,
                                                  float* __restrict__ tbuf) {
    int wg = blockIdx.x;                       // 1568 = 8 xcd * (4 b * 49 ng)
    int b  = (wg & 7) * 4 + (wg >> 3) / 49;
    int ng = (wg >> 3) % 49;
    int t = threadIdx.x, g = t >> 6, l = t & 63;
    int h = l >> 4, m16 = l & 15;
    int kb = (g & 1) * 3;

    const ushort* fh = xfh + (((size_t)(b * NGRP + ng)) * 6 + kb) * 512 + (size_t)l * 8;
    const ushort* fl = xfl + (((size_t)(b * NGRP + ng)) * 6 + kb) * 512 + (size_t)l * 8;
    s8v xh[3], xl[3];
#pragma unroll
    for (int kk = 0; kk < 3; ++kk) {
        xh[kk] = *(const s8v*)(fh + kk * 512);
        xl[kk] = *(const s8v*)(fl + kk * 512);
    }

    for (int ogg = 0; ogg < 6; ++ogg) {
        int row = g * 96 + ogg * 16 + m16;     // global out-channel
        const float* wr = w + row * 96 + h * 8;
        s8v wh[3], wl[3];
#pragma unroll
        for (int kk = 0; kk < 3; ++kk) {
            float4 wa = *(const float4*)(wr + kk * 32);
            float4 wb = *(const float4*)(wr + kk * 32 + 4);
            float vv[8] = {wa.x, wa.y, wa.z, wa.w, wb.x, wb.y, wb.z, wb.w};
#pragma unroll
            for (int k = 0; k < 8; ++k) {
                ushort hh = bf16_rne(vv[k]);
                wh[kk][k] = (short)hh;
                wl[kk][k] = (short)bf16_rne(vv[k] - bf16f(hh));
            }
        }
        f4v acc = {0.f, 0.f, 0.f, 0.f};
#pragma unroll
        for (int kk = 0; kk < 3; ++kk) {
            acc = __builtin_amdgcn_mfma_f32_16x16x32_bf16(xh[kk], wh[kk], acc, 0, 0, 0);
            acc = __builtin_amdgcn_mfma_f32_16x16x32_bf16(xh[kk], wl[kk], acc, 0, 0, 0);
            acc = __builtin_amdgcn_mfma_f32_16x16x32_bf16(xl[kk], wh[kk], acc, 0, 0, 0);
        }
        // D: n = ng*16 + h*4 + r, og-col = m16
        if (g < 2) {
            float bv = bias[row];
#pragma unroll
            for (int r = 0; r < 4; ++r) {
                int n = ng * 16 + h * 4 + r;
                out[((size_t)b * OUTC + row) * NPIX + n] = gelu_exact(acc[r] + bv);
            }
        } else {
            int r2 = (g - 2) * 96 + ogg * 16 + m16;
#pragma unroll
            for (int r = 0; r < 4; ++r) {
                int n = ng * 16 + h * 4 + r;
                tbuf[((size_t)b * 192 + r2) * NPIX + n] = acc[r];
            }
        }
    }
}

// ---------------- K4: groups 2/3  out = max_k gelu(t[idx_k] - t[n] + bias) ----------------
// gelu is unimodal (min at u*~-0.752): max over set = max(gelu(umin), gelu(umax))
__global__ __launch_bounds__(256) void k4_gather(const float* __restrict__ tbuf,
                                                 const int* __restrict__ nnidx,
                                                 const float* __restrict__ bias,
                                                 float* __restrict__ out) {
    __shared__ float trow[NPIX];
    int og2 = blockIdx.x;    // 0..191
    int b = blockIdx.y;
    int t = threadIdx.x;
    const float* tr = tbuf + ((size_t)b * 192 + og2) * NPIX;
    for (int i = t; i < NPIX; i += 256) trow[i] = tr[i];
    __syncthreads();
    float bv = bias[192 + og2];
    for (int n = t; n < NPIX; n += 256) {
        float ti = trow[n];
        const int* ip = nnidx + ((size_t)b * NPIX + n) * KNN;
        float umin = 3.4e38f, umax = -3.4e38f;
#pragma unroll
        for (int k = 0; k < KNN; ++k) {
            int j = ip[k];
            float u = trow[j] - ti + bv;
            umin = fminf(umin, u);
            umax = fmaxf(umax, u);
        }
        float m = fmaxf(gelu_exact(umin), gelu_exact(umax));
        out[((size_t)b * OUTC + 192 + og2) * NPIX + n] = m;
    }
}

extern "C" void kernel_launch(void* const* d_in, const int* in_sizes, int n_in,
                              void* d_out, int out_size, void* d_ws, size_t ws_size,
                              hipStream_t stream) {
    const float* x    = (const float*)d_in[0];
    const float* w    = (const float*)d_in[1];
    const float* bias = (const float*)d_in[2];
    float* out = (float*)d_out;
    char* ws = (char*)d_ws;

    ushort* xfh   = (ushort*)(ws);
    ushort* xfl   = (ushort*)(ws + XFH_BYTES);
    float2* pair  = (float2*)(ws + XFH_BYTES + XFL_BYTES);
    int*    nnidx = (int*)   (ws + XFH_BYTES + XFL_BYTES + PAIR_BYTES);
    float*  tbuf  = (float*) (ws + XFH_BYTES + XFL_BYTES + PAIR_BYTES + IDX_BYTES);

    k1_normalize<<<dim3(NP / 64, BSZ), 256, 0, stream>>>(x, xfh, xfl, pair);
    k2_knn<<<dim3(1568), 128, 0, stream>>>(xfh, xfl, (const float*)pair, nnidx);
    k3_proj<<<dim3(1568), 256, 0, stream>>>(xfh, xfl, w, bias, out, tbuf);
    k4_gather<<<dim3(192, BSZ), 256, 0, stream>>>(tbuf, nnidx, bias, out);
}